// Round 3
// baseline (656.881 us; speedup 1.0000x reference)
//
#include <hip/hip_runtime.h>
#include <stdint.h>

#define NVOX 400000
#define KTAPS 27
// CIN = COUT = 64; 400000 = 3125 blocks * 128 voxels exactly.

typedef __bf16 bf16x8 __attribute__((ext_vector_type(8)));
typedef float floatx16 __attribute__((ext_vector_type(16)));

__device__ __forceinline__ uint32_t f2bf(float f) {
  uint32_t u = __builtin_bit_cast(uint32_t, f);
  u += 0x7fffu + ((u >> 16) & 1u);
  return u >> 16;
}

__device__ __forceinline__ floatx16 zero16() {
  floatx16 z = {0.f,0.f,0.f,0.f,0.f,0.f,0.f,0.f,
                0.f,0.f,0.f,0.f,0.f,0.f,0.f,0.f};
  return z;
}

// Fused precompute. DO_F: blocks [0,6250) convert feats fp32->bf16; blocks
// [6250,6682) convert+transpose weight (Wt[k][co][ci]); block 6250 also
// writes the zero row at featsb[NVOX] (gather target for idx==-1).
template<bool DO_F>
__global__ void k_pre(const float* __restrict__ W, const float4* __restrict__ F,
                      unsigned short* __restrict__ Wt, uint2* __restrict__ Fb) {
  int b = blockIdx.x;
  int t = threadIdx.x;
  if (DO_F && b < 6250) {
    int i0 = b * 1024 + t;
#pragma unroll
    for (int j = 0; j < 4; ++j) {
      int i = i0 + j * 256;
      float4 v = F[i];
      uint2 o;
      o.x = f2bf(v.x) | (f2bf(v.y) << 16);
      o.y = f2bf(v.z) | (f2bf(v.w) << 16);
      Fb[i] = o;
    }
  } else if (b >= 6250) {
    int wb = b - 6250;
    int i = wb * 256 + t;
    int k = i >> 12;
    int rem = i & 4095;
    int ci = rem >> 6, co = rem & 63;
    Wt[(k << 12) + (co << 6) + ci] = (unsigned short)f2bf(W[i]);
    if (DO_F && wb == 0 && t < 16) {
      uint2 z; z.x = 0u; z.y = 0u;
      Fb[(size_t)NVOX * 16 + t] = z;
    }
  }
}

// Barrier-free, LDS-free conv. Block = 256 thr = 4 independent waves.
// Wave: 32 voxels x 64 couts (2x mfma_f32_32x32x16_bf16 per k-chunk).
// A frag (row=lane&31, k=(lane>>5)*8+j) gathered straight from featsb;
// B frag from Wt[k][co][ci] (8KB/tap, L1/L2-hot). A double-buffered 1 tap
// ahead, idx 2 taps ahead; idx==-1 gathers the zero row at featsb[NVOX].
// XCD swizzle: grid 3128, vb=(b&7)*391+(b>>3) -> resident per-XCD gather
// footprint ~1.3MB (fits 4MB L2).
template<bool FAST>
__global__ __launch_bounds__(256, 4) void k_conv(
    const float* __restrict__ feats,            // fp32 (fallback path)
    const unsigned short* __restrict__ featsb,  // [NVOX+1][64] bf16
    const unsigned short* __restrict__ Wt,      // [27][64][64] bf16 [k][co][ci]
    const float* __restrict__ bias,
    const int* __restrict__ nbr,                // [27][NVOX]
    float* __restrict__ out) {                  // [NVOX][64] fp32

  int b = blockIdx.x;
  int vb = (b & 7) * 391 + (b >> 3);
  if (vb >= 3125) return;

  const int t = threadIdx.x;
  const int w = t >> 6;
  const int l = t & 63;
  const int half = l >> 5;
  const int lm = l & 31;
  const int row = vb * 128 + w * 32 + lm;       // this lane's A voxel row
  const int aoffh = half * 16;                  // byte offset within 128 B row
  const int bo = lm * 128 + half * 16;          // B frag byte offset (N-tile 0)

  const char* FBp = (const char*)featsb;
  const char* WBp = (const char*)Wt;

  floatx16 acc0 = zero16(), acc1 = zero16();

  uint4 A0[4], A1[4], Bt[8];                    // Bt[nt*4+kc]

  auto loadA = [&](uint4* A, int idx) {
    if (FAST) {
      int safe = idx < 0 ? NVOX : idx;
      const char* ar = FBp + (size_t)safe * 128 + aoffh;
#pragma unroll
      for (int kc = 0; kc < 4; ++kc) A[kc] = *(const uint4*)(ar + kc * 32);
    } else {
      int safe = idx < 0 ? 0 : idx;
      const char* ar = (const char*)feats + (size_t)safe * 256 + aoffh * 2;
#pragma unroll
      for (int kc = 0; kc < 4; ++kc) {
        float4 f0 = *(const float4*)(ar + kc * 64);
        float4 f1 = *(const float4*)(ar + kc * 64 + 16);
        uint4 d;
        d.x = f2bf(f0.x) | (f2bf(f0.y) << 16);
        d.y = f2bf(f0.z) | (f2bf(f0.w) << 16);
        d.z = f2bf(f1.x) | (f2bf(f1.y) << 16);
        d.w = f2bf(f1.z) | (f2bf(f1.w) << 16);
        if (idx < 0) { d.x = 0; d.y = 0; d.z = 0; d.w = 0; }
        A[kc] = d;
      }
    }
  };
  auto loadB = [&](int k) {
    const char* wk = WBp + (size_t)k * 8192 + bo;
#pragma unroll
    for (int kc = 0; kc < 4; ++kc) {
      Bt[kc]     = *(const uint4*)(wk + kc * 32);
      Bt[4 + kc] = *(const uint4*)(wk + 4096 + kc * 32);
    }
  };
  auto mfma8 = [&](const uint4* A) {
#pragma unroll
    for (int kc = 0; kc < 4; ++kc) {
      bf16x8 a  = __builtin_bit_cast(bf16x8, A[kc]);
      bf16x8 b0 = __builtin_bit_cast(bf16x8, Bt[kc]);
      bf16x8 b1 = __builtin_bit_cast(bf16x8, Bt[4 + kc]);
      acc0 = __builtin_amdgcn_mfma_f32_32x32x16_bf16(a, b0, acc0, 0, 0, 0);
      acc1 = __builtin_amdgcn_mfma_f32_32x32x16_bf16(a, b1, acc1, 0, 0, 0);
    }
  };

  // ---- prologue: tap0 A+B, tap1 idx ----
  int id0 = nbr[row];
  loadA(A0, id0);
  int idn = nbr[NVOX + row];                    // idx for tap 1
  loadB(0);

  // ---- main loop: 13 double-taps (taps 0..25), tail tap 26 ----
#pragma unroll 1
  for (int kk = 0; kk < 13; ++kk) {
    const int e = kk * 2;                       // even tap; A0 current
    loadA(A1, idn);                             // prefetch A for tap e+1
    int idn2 = nbr[(size_t)(e + 2) * NVOX + row];
    mfma8(A0);                                  // tap e
    loadB(e + 1);
    loadA(A0, idn2);                            // prefetch A for tap e+2
    int k3 = (e + 3 > 26) ? 26 : (e + 3);
    idn = nbr[(size_t)k3 * NVOX + row];
    mfma8(A1);                                  // tap e+1
    loadB(e + 2);
  }
  mfma8(A0);                                    // tap 26

  // ---- epilogue: C/D layout col=lane&31 (cout), row=(reg&3)+8*(reg>>2)+4*half
  float bv0 = bias[lm];
  float bv1 = bias[32 + lm];
#pragma unroll
  for (int reg = 0; reg < 16; ++reg) {
    int m = (reg & 3) + 8 * (reg >> 2) + 4 * half;
    int vm = vb * 128 + w * 32 + m;
    out[vm * 64 + lm]      = acc0[reg] + bv0;
    out[vm * 64 + 32 + lm] = acc1[reg] + bv1;
  }
}

extern "C" void kernel_launch(void* const* d_in, const int* in_sizes, int n_in,
                              void* d_out, int out_size, void* d_ws, size_t ws_size,
                              hipStream_t stream) {
  const float* feats  = (const float*)d_in[0];
  const float* weight = (const float*)d_in[1];
  const float* bias   = (const float*)d_in[2];
  const int*   nbr    = (const int*)d_in[3];
  float* out = (float*)d_out;

  unsigned short* Wt = (unsigned short*)d_ws;
  const size_t featsOff = 256 * 1024;                       // Wt uses 221184 B
  const size_t fbytes = (size_t)(NVOX + 1) * 64 * 2;        // bf16 feats + zero row
  const bool bigws = ws_size >= featsOff + fbytes;          // constant -> graph-safe

  if (bigws) {
    unsigned short* Fb = (unsigned short*)((char*)d_ws + featsOff);
    k_pre<true><<<6682, 256, 0, stream>>>(weight, (const float4*)feats, Wt, (uint2*)Fb);
    k_conv<true><<<3128, 256, 0, stream>>>(feats, Fb, Wt, bias, nbr, out);
  } else {
    k_pre<false><<<6682, 256, 0, stream>>>(weight, (const float4*)feats, Wt, nullptr);
    k_conv<false><<<3128, 256, 0, stream>>>(feats, nullptr, Wt, bias, nbr, out);
  }
}

// Round 4
// 378.367 us; speedup vs baseline: 1.7361x; 1.7361x over previous
//
#include <hip/hip_runtime.h>
#include <stdint.h>

#define NVOX 400000
#define KTAPS 27
// CIN = COUT = 64; 400000 = 3125 blocks * 128 voxels exactly.

typedef __bf16 bf16x8 __attribute__((ext_vector_type(8)));
typedef float floatx4 __attribute__((ext_vector_type(4)));

__device__ __forceinline__ uint32_t f2bf(float f) {
  uint32_t u = __builtin_bit_cast(uint32_t, f);
  u += 0x7fffu + ((u >> 16) & 1u);
  return u >> 16;
}

// Fused precompute.
// DO_F: blocks [0,6250) convert feats fp32->bf16 (4 float4/thread);
// blocks [FOFF, FOFF+54) build Wfrag in MFMA B-fragment order:
//   Wfrag[tap][nt2][lane] (16 B) = { W[tap][ci0+j][co] : j=0..7 } as bf16,
//   nt2 = nt*2+kc, ci0 = kc*32+(lane>>4)*8, co = nt*16+(lane&15).
// First Wfrag block also writes the zero row at featsb[NVOX].
template<bool DO_F>
__global__ void k_pre(const float* __restrict__ W, const float4* __restrict__ F,
                      uint4* __restrict__ Wf, uint2* __restrict__ Fb) {
  const int FOFF = DO_F ? 6250 : 0;
  int b = blockIdx.x;
  int t = threadIdx.x;
  if (DO_F && b < 6250) {
    int i0 = b * 1024 + t;
#pragma unroll
    for (int j = 0; j < 4; ++j) {
      int i = i0 + j * 256;
      float4 v = F[i];
      uint2 o;
      o.x = f2bf(v.x) | (f2bf(v.y) << 16);
      o.y = f2bf(v.z) | (f2bf(v.w) << 16);
      Fb[i] = o;
    }
  } else if (b >= FOFF) {
    int id = (b - FOFF) * 256 + t;        // [0, 13824)
    int tap = id >> 9;                    // /512
    int r = id & 511;
    int nt2 = r >> 6;
    int l = r & 63;
    int kc = nt2 & 1, nt = nt2 >> 1;
    int ci0 = kc * 32 + (l >> 4) * 8;
    int co = nt * 16 + (l & 15);
    const float* src = W + tap * 4096 + ci0 * 64 + co;
    uint4 d;
    uint32_t* dp = (uint32_t*)&d;
#pragma unroll
    for (int p = 0; p < 4; ++p) {
      float a = src[(2 * p) * 64];
      float c = src[(2 * p + 1) * 64];
      dp[p] = f2bf(a) | (f2bf(c) << 16);
    }
    Wf[id] = d;
    if (DO_F && (b - FOFF) == 0 && t < 16) {
      uint2 z; z.x = 0u; z.y = 0u;
      Fb[(size_t)NVOX * 16 + t] = z;
    }
  }
}

// Barrier-free, LDS-free conv. Block = 256 thr = 4 independent waves.
// Wave: 32 voxels (2 M-tiles of 16) x 64 couts (4 N-tiles), mfma 16x16x32.
// A frag gathered direct from featsb: lanes l,l+16,l+32,l+48 read 64
// contiguous bytes of one voxel row -> 16 fully-used 64B sectors per
// instruction. B frags from Wfrag (fragment-major, perfectly coalesced,
// L1-hot 8KB/tap), single-buffered: Bv[nt2] reloaded for tap k+1 right
// after its 2 consuming MFMAs. A double-buffered 1 tap ahead, idx 2 ahead.
// __launch_bounds__(256,3): ~170 VGPR cap, no spill (R3 lesson: spill at
// (256,4) cost 2.7x). idx==-1 gathers the zero row at featsb[NVOX].
template<bool FAST>
__global__ __launch_bounds__(256, 3) void k_conv(
    const float* __restrict__ feats,            // fp32 (fallback path)
    const unsigned short* __restrict__ featsb,  // [NVOX+1][64] bf16
    const uint4* __restrict__ Wf,               // fragment-major B table
    const float* __restrict__ bias,
    const int* __restrict__ nbr,                // [27][NVOX]
    float* __restrict__ out) {                  // [NVOX][64] fp32

  int b = blockIdx.x;
  int vb = (b & 7) * 391 + (b >> 3);            // XCD-aware swizzle
  if (vb >= 3125) return;

  const int t = threadIdx.x;
  const int w = t >> 6;
  const int l = t & 63;
  const int q = l >> 4;                         // quad 0..3
  const int m = l & 15;
  const int W0 = vb * 128 + w * 32;             // wave's first voxel
  const int aoff = q * 16;                      // byte offset in bf16 row

  const char* FBp = (const char*)featsb;
  const char* WFp = (const char*)Wf;

  floatx4 acc[2][4];
#pragma unroll
  for (int mt = 0; mt < 2; ++mt)
#pragma unroll
    for (int nt = 0; nt < 4; ++nt) {
      floatx4 z = {0.f, 0.f, 0.f, 0.f};
      acc[mt][nt] = z;
    }

  uint4 A0[4], A1[4], Bv[8];                    // A[mt*2+kc], Bv[nt2]

  auto loadA = [&](uint4* A, const int* idx2) {
#pragma unroll
    for (int mt = 0; mt < 2; ++mt) {
      int idx = idx2[mt];
      if (FAST) {
        int safe = idx < 0 ? NVOX : idx;
        const char* ar = FBp + (size_t)safe * 128 + aoff;
        A[mt * 2 + 0] = *(const uint4*)ar;
        A[mt * 2 + 1] = *(const uint4*)(ar + 64);
      } else {
        int safe = idx < 0 ? 0 : idx;
        const char* ar = (const char*)feats + (size_t)safe * 256 + q * 32;
#pragma unroll
        for (int kc = 0; kc < 2; ++kc) {
          float4 f0 = *(const float4*)(ar + kc * 128);
          float4 f1 = *(const float4*)(ar + kc * 128 + 16);
          uint4 d;
          d.x = f2bf(f0.x) | (f2bf(f0.y) << 16);
          d.y = f2bf(f0.z) | (f2bf(f0.w) << 16);
          d.z = f2bf(f1.x) | (f2bf(f1.y) << 16);
          d.w = f2bf(f1.z) | (f2bf(f1.w) << 16);
          if (idx < 0) { d.x = 0; d.y = 0; d.z = 0; d.w = 0; }
          A[mt * 2 + kc] = d;
        }
      }
    }
  };
  auto loadIdx = [&](int k, int* idx2) {
    const int* nb = nbr + (size_t)k * NVOX + W0 + m;
    idx2[0] = nb[0];
    idx2[1] = nb[16];
  };
  auto loadBk = [&](int nt2, int k) {
    Bv[nt2] = *(const uint4*)(WFp + (size_t)k * 8192 + nt2 * 1024 + l * 16);
  };
  // tap compute: 16 MFMAs; Bv[nt2] rotated to tap knext right after use.
  auto tapCompute = [&](const uint4* A, int knext) {
#pragma unroll
    for (int nt2 = 0; nt2 < 8; ++nt2) {
      int nt = nt2 >> 1, kc = nt2 & 1;
      bf16x8 bb = __builtin_bit_cast(bf16x8, Bv[nt2]);
      acc[0][nt] = __builtin_amdgcn_mfma_f32_16x16x32_bf16(
          __builtin_bit_cast(bf16x8, A[kc]), bb, acc[0][nt], 0, 0, 0);
      acc[1][nt] = __builtin_amdgcn_mfma_f32_16x16x32_bf16(
          __builtin_bit_cast(bf16x8, A[2 + kc]), bb, acc[1][nt], 0, 0, 0);
      loadBk(nt2, knext);
    }
  };

  // ---- prologue: tap0 A+B, tap1 idx ----
  int idA[2], idN[2];
  loadIdx(0, idA);
  loadA(A0, idA);
#pragma unroll
  for (int nt2 = 0; nt2 < 8; ++nt2) loadBk(nt2, 0);
  loadIdx(1, idN);

  // ---- main loop: 13 double-taps (taps 0..25), tail tap 26 ----
#pragma unroll 1
  for (int kk = 0; kk < 13; ++kk) {
    const int e = kk * 2;
    loadA(A1, idN);                 // gather A for tap e+1
    loadIdx(e + 2, idA);            // idx for tap e+2
    tapCompute(A0, e + 1);          // tap e; rotates Bv -> B[e+1]
    loadA(A0, idA);                 // gather A for tap e+2
    int k3 = (e + 3 > 26) ? 26 : (e + 3);
    loadIdx(k3, idN);
    tapCompute(A1, e + 2);          // tap e+1; rotates Bv -> B[e+2]
  }
  tapCompute(A0, 26);               // tap 26 (Bv reload harmless)

  // ---- epilogue: C/D col=lane&15, row=q*4+reg; nontemporal (out streams,
  // keep L2 for featsb gathers) ----
  float bv[4];
#pragma unroll
  for (int nt = 0; nt < 4; ++nt) bv[nt] = bias[nt * 16 + m];
#pragma unroll
  for (int mt = 0; mt < 2; ++mt)
#pragma unroll
    for (int nt = 0; nt < 4; ++nt)
#pragma unroll
      for (int reg = 0; reg < 4; ++reg) {
        int vox = W0 + mt * 16 + q * 4 + reg;
        float val = acc[mt][nt][reg] + bv[nt];
        __builtin_nontemporal_store(val, out + (size_t)vox * 64 + nt * 16 + m);
      }
}

extern "C" void kernel_launch(void* const* d_in, const int* in_sizes, int n_in,
                              void* d_out, int out_size, void* d_ws, size_t ws_size,
                              hipStream_t stream) {
  const float* feats  = (const float*)d_in[0];
  const float* weight = (const float*)d_in[1];
  const float* bias   = (const float*)d_in[2];
  const int*   nbr    = (const int*)d_in[3];
  float* out = (float*)d_out;

  uint4* Wf = (uint4*)d_ws;                                 // 221184 B
  const size_t featsOff = 256 * 1024;
  const size_t fbytes = (size_t)(NVOX + 1) * 64 * 2;        // bf16 feats + zero row
  const bool bigws = ws_size >= featsOff + fbytes;          // constant -> graph-safe

  if (bigws) {
    unsigned short* Fb = (unsigned short*)((char*)d_ws + featsOff);
    k_pre<true><<<6304, 256, 0, stream>>>(weight, (const float4*)feats, Wf, (uint2*)Fb);
    k_conv<true><<<3128, 256, 0, stream>>>(feats, (const unsigned short*)Fb, Wf,
                                           bias, nbr, out);
  } else {
    k_pre<false><<<54, 256, 0, stream>>>(weight, (const float4*)feats, Wf, nullptr);
    k_conv<false><<<3128, 256, 0, stream>>>(feats, nullptr, Wf, bias, nbr, out);
  }
}